// Round 10
// baseline (2221.362 us; speedup 1.0000x reference)
//
#include <hip/hip_runtime.h>
#include <hip/hip_bf16.h>

// ConvGRU: fused cell kernels (2 dispatches/step), NO state staging.
// A-fragments stream directly from global (coalesced 256B/tap/m-tile, L1/L2
// resident). Gates computed halo-redundantly over the 6x34 ring; epilogue
// stores only r (fp16) to LDS; z stays in the computing wave's registers
// (gates/cand C-layouts match). Cand reconstructs r*h as r_frag*h_frag
// (packed f16 mul). h_new epilogue is vectorized via an (n,z)-packed LDS
// bounce -> b128 global load/store. States fp16 NHWC, 2-px zero halo,
// double-buffered: S[B][134][134][32] x4 planes.
// fp16 MFMA 16x16x32, fp32 acc (absmax ~1e-3 vs threshold 3.36e-3).

#define HH 128
#define PH2 134
#define HW 16384
#define BB 8
#define TT 16

typedef _Float16 f16x8 __attribute__((ext_vector_type(8)));
typedef float f32x4 __attribute__((ext_vector_type(4)));
typedef unsigned int u32x4 __attribute__((ext_vector_type(4)));

#define RPLANE 1640     // r-buf plane stride in ushorts (204*8 + 8 pad)
#define BPAD 36         // bounce pixel stride in u32 (16B-aligned, bank-skewed)

__device__ __forceinline__ unsigned short f2h(float x){
    return __builtin_bit_cast(unsigned short, (_Float16)x);
}
__device__ __forceinline__ float h2f(unsigned short u){
    return (float)__builtin_bit_cast(_Float16, u);
}
__device__ __forceinline__ f16x8 ld_frag(const unsigned short* p){
    u32x4 v = *(const u32x4*)p;
    return __builtin_bit_cast(f16x8, v);
}
__device__ __forceinline__ float sigmoid_f(float a){ return 1.0f / (1.0f + __expf(-a)); }
__device__ __forceinline__ float tanh_f(float a){ float e2 = __expf(2.0f * a); return 1.0f - 2.0f / (e2 + 1.0f); }

// ring position (0..75, clamped) -> region coords in the 6x34 gate region
__device__ __forceinline__ void ring_rc(int ri, int& r, int& c){
    ri = ri > 75 ? 75 : ri;
    if (ri < 34)      { r = 0; c = ri; }
    else if (ri < 68) { r = 5; c = ri - 34; }
    else { int e = ri - 68; r = 1 + (e >> 1); c = (e & 1) * 33; }
}

// ---- weight prep: [cout][cin_tot][9] fp32 -> [step][cout][32] fp16 ----
__global__ void prep_w(const float* __restrict__ w, unsigned short* __restrict__ wf,
                       int CO, int CIT, int NSTEP, int xmode)
{
    int idx = blockIdx.x * 256 + threadIdx.x;
    int total = NSTEP * CO * 32;
    if (idx >= total) return;
    int kk = idx & 31;
    int t  = idx >> 5;
    int co = t % CO;
    int s  = t / CO;
    float v = 0.0f;
    if (xmode && s == NSTEP - 1) {
        if (kk < 9) v = w[(co * CIT + 0) * 9 + kk];
    } else {
        int tap = s % 9;
        int cin = (s / 9) * 32 + kk + (xmode ? 1 : 0);
        v = w[(co * CIT + cin) * 9 + tap];
    }
    wf[idx] = f2h(v);
}

// gates conv for one m-tile; per-lane A-row region coords (prl, pcl).
template<bool L0I>
__device__ __forceinline__ void gates_conv(
    f32x4 acc[4], int prl, int pcl, long fb,
    const unsigned short* __restrict__ PA, const unsigned short* __restrict__ PB,
    const unsigned short* xs, const unsigned short* __restrict__ Wg,
    int q, int m, const float* __restrict__ bg)
{
#pragma unroll
    for (int ng = 0; ng < 4; ++ng){ float bv = bg[ng*16+m]; acc[ng] = f32x4{bv,bv,bv,bv}; }
#pragma unroll 3
    for (int s = 0; s < 9; ++s){
        int ty = s/3, tx = s%3;
        long ga = (fb + (long)((prl+ty)*PH2 + pcl+tx))*32 + q*8;
        f16x8 A = ld_frag(PA + ga);
#pragma unroll
        for (int ng = 0; ng < 4; ++ng){
            f16x8 B = ld_frag(Wg + (s*64 + ng*16 + m)*32 + q*8);
            acc[ng] = __builtin_amdgcn_mfma_f32_16x16x32_f16(A, B, acc[ng], 0, 0, 0);
        }
    }
    if (L0I){
        f16x8 A;
#pragma unroll
        for (int j = 0; j < 8; ++j){
            int k = q*8 + j;
            unsigned short xv = 0;
            if (k < 9) xv = xs[(prl + k/3)*37 + pcl + k%3];
            A[j] = __builtin_bit_cast(_Float16, xv);
        }
#pragma unroll
        for (int ng = 0; ng < 4; ++ng){
            f16x8 B = ld_frag(Wg + (9*64 + ng*16 + m)*32 + q*8);
            acc[ng] = __builtin_amdgcn_mfma_f32_16x16x32_f16(A, B, acc[ng], 0, 0, 0);
        }
    } else {
#pragma unroll 3
        for (int s = 9; s < 18; ++s){
            int t2 = s - 9, ty = t2/3, tx = t2%3;
            long ga = (fb + (long)((prl+ty)*PH2 + pcl+tx))*32 + q*8;
            f16x8 A = ld_frag(PB + ga);
#pragma unroll
            for (int ng = 0; ng < 4; ++ng){
                f16x8 B = ld_frag(Wg + (s*64 + ng*16 + m)*32 + q*8);
                acc[ng] = __builtin_amdgcn_mfma_f32_16x16x32_f16(A, B, acc[ng], 0, 0, 0);
            }
        }
    }
}

// ---- fused GRU cell. 256 thr (4 waves), tile 4x32; grid (128, B). ----
template<int LAYER>
__global__ __launch_bounds__(256, 4)
void cell_kernel(const unsigned short* __restrict__ PA,   // L0: h0_prev, L1: h0_new
                 const unsigned short* __restrict__ PB,   // L1: h1_prev
                 unsigned short* __restrict__ Sout,
                 const float* __restrict__ xraw, long xbs,
                 const unsigned short* __restrict__ Wg,
                 const unsigned short* __restrict__ Wc,
                 const float* __restrict__ bg, const float* __restrict__ bc)
{
    constexpr bool L0 = (LAYER == 0);
    __shared__ __align__(16) unsigned short rbuf[4 * RPLANE];   // r, octet-major
    __shared__ __align__(16) unsigned int bounce[128 * BPAD];   // (z|n) packed
    __shared__ unsigned short xs[L0 ? 296 : 2];                 // 8x37 fp16

    const int b = blockIdx.y;
    const int tc = blockIdx.x & 3, tr = blockIdx.x >> 2;
    const int row0 = tr * 4, col0 = tc * 32;
    const int wv = threadIdx.x >> 6, lane = threadIdx.x & 63;
    const int m = lane & 15, q = lane >> 4;
    const long fb = ((long)(b * PH2 + row0)) * PH2 + col0;   // frame pixel base

    if (L0){
        const float* xb = xraw + (long)b * xbs;
        for (int p = threadIdx.x; p < 296; p += 256){
            int r = p / 37, c = p - r * 37;
            int ir = row0 - 2 + r, ic = col0 - 2 + c;
            float v = 0.0f;
            if (ir >= 0 && ir < HH && ic >= 0 && ic < HH) v = xb[ir * HH + ic];
            xs[p] = f2h(v);
        }
        __syncthreads();
    }

    // ---------------- GATES ----------------
    f32x4 zsv[2][2];
    // interior tiles: it = s2*4 + wv  (pixels row 1+(it>>1), cols 1+(it&1)*16)
#pragma unroll
    for (int s2 = 0; s2 < 2; ++s2){
        const int it = s2 * 4 + wv;
        const int gr = 1 + (it >> 1);
        const int gcb = 1 + (it & 1) * 16;
        f32x4 acc[4];
        gates_conv<L0>(acc, gr, gcb + m, fb, PA, PB, xs, Wg, q, m, bg);
#pragma unroll
        for (int ng = 0; ng < 2; ++ng)
#pragma unroll
            for (int rg = 0; rg < 4; ++rg){
                int p = gr * 34 + gcb + q * 4 + rg;
                int n = ng * 16 + m;
                rbuf[(n >> 3) * RPLANE + p * 8 + (n & 7)] = f2h(sigmoid_f(acc[ng][rg]));
            }
#pragma unroll
        for (int e = 0; e < 4; ++e){
            zsv[s2][0][e] = sigmoid_f(acc[2][e]);
            zsv[s2][1][e] = sigmoid_f(acc[3][e]);
        }
    }
    // ring tiles rt = wv (+4 for wave 0): 76 ring px in 5 tiles (clamped dups)
#pragma unroll
    for (int s2 = 0; s2 < 2; ++s2){
        const int rt = s2 * 4 + wv;
        if (rt < 5){
            int prl, pcl; ring_rc(rt * 16 + m, prl, pcl);
            f32x4 acc[4];
            gates_conv<L0>(acc, prl, pcl, fb, PA, PB, xs, Wg, q, m, bg);
#pragma unroll
            for (int ng = 0; ng < 2; ++ng)
#pragma unroll
                for (int rg = 0; rg < 4; ++rg){
                    int er, ec; ring_rc(rt * 16 + q * 4 + rg, er, ec);
                    int n = ng * 16 + m;
                    rbuf[(n >> 3) * RPLANE + (er * 34 + ec) * 8 + (n & 7)] = f2h(sigmoid_f(acc[ng][rg]));
                }
        }
    }
    __syncthreads();

    // ---------------- CANDIDATE (same-wave tiles -> z in regs) -----------
#pragma unroll
    for (int s2 = 0; s2 < 2; ++s2){
        const int it = s2 * 4 + wv;
        const int gr = 1 + (it >> 1);
        const int gcb = 1 + (it & 1) * 16;
        f32x4 acc[2];
#pragma unroll
        for (int ng = 0; ng < 2; ++ng){ float bv = bc[ng*16+m]; acc[ng] = f32x4{bv,bv,bv,bv}; }
        if (L0){
#pragma unroll 3
            for (int s = 0; s < 9; ++s){            // r * h0 taps
                int ty = s/3, tx = s%3;
                int pr = (gr + ty - 1) * 34 + gcb + tx - 1 + m;
                f16x8 R = ld_frag(rbuf + q * RPLANE + pr * 8);
                long ga = (fb + (long)((gr+ty)*PH2 + gcb+tx+m))*32 + q*8;
                f16x8 Hv = ld_frag(PA + ga);
                f16x8 A = R * Hv;
#pragma unroll
                for (int ng = 0; ng < 2; ++ng){
                    f16x8 B = ld_frag(Wc + (s*32 + ng*16 + m)*32 + q*8);
                    acc[ng] = __builtin_amdgcn_mfma_f32_16x16x32_f16(A, B, acc[ng], 0, 0, 0);
                }
            }
            f16x8 A;                                 // x im2col step
#pragma unroll
            for (int j = 0; j < 8; ++j){
                int k = q*8 + j;
                unsigned short xv = 0;
                if (k < 9) xv = xs[(gr + k/3)*37 + gcb + m + k%3];
                A[j] = __builtin_bit_cast(_Float16, xv);
            }
#pragma unroll
            for (int ng = 0; ng < 2; ++ng){
                f16x8 B = ld_frag(Wc + (9*32 + ng*16 + m)*32 + q*8);
                acc[ng] = __builtin_amdgcn_mfma_f32_16x16x32_f16(A, B, acc[ng], 0, 0, 0);
            }
        } else {
#pragma unroll 3
            for (int s = 0; s < 9; ++s){            // h0 taps (plain)
                int ty = s/3, tx = s%3;
                long ga = (fb + (long)((gr+ty)*PH2 + gcb+tx+m))*32 + q*8;
                f16x8 A = ld_frag(PA + ga);
#pragma unroll
                for (int ng = 0; ng < 2; ++ng){
                    f16x8 B = ld_frag(Wc + (s*32 + ng*16 + m)*32 + q*8);
                    acc[ng] = __builtin_amdgcn_mfma_f32_16x16x32_f16(A, B, acc[ng], 0, 0, 0);
                }
            }
#pragma unroll 3
            for (int s = 9; s < 18; ++s){           // r * h1 taps
                int t2 = s - 9, ty = t2/3, tx = t2%3;
                int pr = (gr + ty - 1) * 34 + gcb + tx - 1 + m;
                f16x8 R = ld_frag(rbuf + q * RPLANE + pr * 8);
                long ga = (fb + (long)((gr+ty)*PH2 + gcb+tx+m))*32 + q*8;
                f16x8 Hv = ld_frag(PB + ga);
                f16x8 A = R * Hv;
#pragma unroll
                for (int ng = 0; ng < 2; ++ng){
                    f16x8 B = ld_frag(Wc + (s*32 + ng*16 + m)*32 + q*8);
                    acc[ng] = __builtin_amdgcn_mfma_f32_16x16x32_f16(A, B, acc[ng], 0, 0, 0);
                }
            }
        }
        // pack (z, tanh(n)) -> bounce; C-layout matches gates z exactly
#pragma unroll
        for (int ng = 0; ng < 2; ++ng)
#pragma unroll
            for (int rg = 0; rg < 4; ++rg){
                float nv = tanh_f(acc[ng][rg]);
                float zz = zsv[s2][ng][rg];
                int pi = (it >> 1) * 32 + (it & 1) * 16 + q * 4 + rg;
                int n = ng * 16 + m;
                bounce[pi * BPAD + n] = ((unsigned)f2h(zz) << 16) | f2h(nv);
            }
    }
    __syncthreads();

    // ---------------- vectorized GRU update + store ----------------------
    const unsigned short* HP = L0 ? PA : PB;
#pragma unroll
    for (int j = 0; j < 2; ++j){
        int e = j * 256 + threadIdx.x;          // 512 groups of 8 ch
        int px = e >> 2, oc = (e & 3) * 8;
        u32x4 w0 = *(const u32x4*)(bounce + px * BPAD + oc);
        u32x4 w1 = *(const u32x4*)(bounce + px * BPAD + oc + 4);
        int prow = px >> 5, pcol = px & 31;
        long ga = (fb + (long)((prow + 2) * PH2 + pcol + 2)) * 32 + oc;
        f16x8 hv = ld_frag(HP + ga);
        f16x8 ov;
#pragma unroll
        for (int k2 = 0; k2 < 8; ++k2){
            unsigned w = k2 < 4 ? w0[k2] : w1[k2 - 4];
            float nv = h2f((unsigned short)(w & 0xffffu));
            float zz = h2f((unsigned short)(w >> 16));
            float h  = (float)hv[k2];
            ov[k2] = (_Float16)((1.0f - zz) * h + zz * nv);
        }
        *(u32x4*)(Sout + ga) = __builtin_bit_cast(u32x4, ov);
    }
}

// ---- final: h1 plane -> d_out NCHW fp32 ----
__global__ void final_out(const unsigned short* __restrict__ S1, float* __restrict__ out)
{
    int i = blockIdx.x * 256 + threadIdx.x;    // B*32*HW = 4194304
    if (i >= BB * 32 * HW) return;
    int pix = i & 16383;
    int t = i >> 14;
    int c = t & 31, b = t >> 5;
    int r = pix >> 7, cc = pix & 127;
    long pg = (long)(b * PH2 + r + 2) * PH2 + cc + 2;
    out[i] = h2f(S1[pg * 32 + c]);
}

extern "C" void kernel_launch(void* const* d_in, const int* in_sizes, int n_in,
                              void* d_out, int out_size, void* d_ws, size_t ws_size,
                              hipStream_t stream)
{
    const float* seq = (const float*)d_in[0];
    const float* gw0 = (const float*)d_in[1];
    const float* gb0 = (const float*)d_in[2];
    const float* cw0 = (const float*)d_in[3];
    const float* cb0 = (const float*)d_in[4];
    const float* gw1 = (const float*)d_in[5];
    const float* gb1 = (const float*)d_in[6];
    const float* cw1 = (const float*)d_in[7];
    const float* cb1 = (const float*)d_in[8];
    float* out = (float*)d_out;

    const size_t PL = (size_t)BB * PH2 * PH2 * 32;   // 4,596,736 fp16 / plane

    char* p = (char*)d_ws;
    unsigned short* S0a = (unsigned short*)p; p += PL * 2;
    unsigned short* S0b = (unsigned short*)p; p += PL * 2;
    unsigned short* S1a = (unsigned short*)p; p += PL * 2;
    unsigned short* S1b = (unsigned short*)p; p += PL * 2;
    unsigned short* WG0 = (unsigned short*)p; p += 20480 * 2;
    unsigned short* WC0 = (unsigned short*)p; p += 10240 * 2;
    unsigned short* WG1 = (unsigned short*)p; p += 36864 * 2;
    unsigned short* WC1 = (unsigned short*)p; p += 18432 * 2;

    // zero all 4 planes (states + 2-px halos; harness poisons ws)
    hipMemsetAsync(S0a, 0, 4 * PL * 2, stream);

    prep_w<<<(10 * 64 * 32 + 255) / 256, 256, 0, stream>>>(gw0, WG0, 64, 33, 10, 1);
    prep_w<<<(10 * 32 * 32 + 255) / 256, 256, 0, stream>>>(cw0, WC0, 32, 33, 10, 1);
    prep_w<<<(18 * 64 * 32 + 255) / 256, 256, 0, stream>>>(gw1, WG1, 64, 64, 18, 0);
    prep_w<<<(18 * 32 * 32 + 255) / 256, 256, 0, stream>>>(cw1, WC1, 32, 64, 18, 0);

    dim3 grid(128, BB), block(256);
    const long xbs = (long)TT * HW;
    unsigned short *h0r = S0a, *h0w = S0b, *h1r = S1a, *h1w = S1b;
    for (int t = 0; t < TT; ++t) {
        const float* xt = seq + (long)t * HW;
        cell_kernel<0><<<grid, block, 0, stream>>>(h0r, h0r, h0w, xt, xbs, WG0, WC0, gb0, cb0);
        cell_kernel<1><<<grid, block, 0, stream>>>(h0w, h1r, h1w, xt, xbs, WG1, WC1, gb1, cb1);
        unsigned short* tmp;
        tmp = h0r; h0r = h0w; h0w = tmp;
        tmp = h1r; h1r = h1w; h1w = tmp;
    }
    final_out<<<(BB * 32 * HW + 255) / 256, 256, 0, stream>>>(h1r, out);
}